// Round 10
// baseline (2376.783 us; speedup 1.0000x reference)
//
#include <hip/hip_runtime.h>
#include <math.h>

#define BSZ 512
#define TT  100
#define NDD 10
#define DSS 6
#define INS 256
#define HID 256
#define CAT 2816   // INS*NDD + HID
#define KZ  320
#define NOUTP 320
#define NOUT 266
#define NBLK 256
#define NTHR 1024

typedef short sh8 __attribute__((ext_vector_type(8)));
typedef float f4  __attribute__((ext_vector_type(4)));
typedef unsigned int u4 __attribute__((ext_vector_type(4)));
typedef unsigned short ushort_t;

__device__ __forceinline__ float sigf(float x) { return 1.0f / (1.0f + expf(-x)); }

__device__ __forceinline__ ushort_t f2bf(float f) {
    union { float f; unsigned int u; } v; v.f = f;
    unsigned int r = (v.u + 0x7FFFu + ((v.u >> 16) & 1u)) >> 16;
    return (ushort_t)r;
}

#define MFMA(a, b, c) __builtin_amdgcn_mfma_f32_16x16x32_bf16((a), (b), (c), 0, 0, 0)
#define ALOAD(p)    __hip_atomic_load((p), __ATOMIC_RELAXED, __HIP_MEMORY_SCOPE_AGENT)
#define ASTORE(p,v) __hip_atomic_store((p), (v), __ATOMIC_RELAXED, __HIP_MEMORY_SCOPE_AGENT)

// sc1 loads bypass L1/L2 (agent-coherent, matches sc1 store visibility).
// "=&v" earlyclobber MANDATORY (round-7 crash: output overlapped pending addr).
__device__ __forceinline__ u4 aload16(const unsigned int* p) {
    u4 r;
    asm volatile("global_load_dwordx4 %0, %1, off sc0 sc1\n\ts_waitcnt vmcnt(0)"
                 : "=&v"(r) : "v"(p) : "memory");
    return r;
}
__device__ __forceinline__ void aload16x4(f4* a, const float* p0, const float* p1,
                                          const float* p2, const float* p3) {
    asm volatile(
        "global_load_dwordx4 %0, %4, off sc0 sc1\n\t"
        "global_load_dwordx4 %1, %5, off sc0 sc1\n\t"
        "global_load_dwordx4 %2, %6, off sc0 sc1\n\t"
        "global_load_dwordx4 %3, %7, off sc0 sc1\n\t"
        "s_waitcnt vmcnt(0)"
        : "=&v"(a[0]), "=&v"(a[1]), "=&v"(a[2]), "=&v"(a[3])
        : "v"(p0), "v"(p1), "v"(p2), "v"(p3)
        : "memory");
}

// ---------------------------------------------------------------------------
// Precompute kernels (unchanged, validated)
// ---------------------------------------------------------------------------
__global__ __launch_bounds__(64) void k_fold(
    const float* __restrict__ W1, const float* __restrict__ Wd,
    const float* __restrict__ bd, const float* __restrict__ b1,
    ushort_t* __restrict__ Wzc, float* __restrict__ bfold)
{
    __shared__ float sW1[2560];
    __shared__ float sWd[INS * DSS];
    __shared__ float red[64];
    const int j = blockIdx.x;
    const int tid = threadIdx.x;
    for (int f = tid; f < INS * DSS; f += 64) sWd[f] = Wd[f];
    for (int f = tid; f < 2560; f += 64) sW1[f] = W1[(size_t)j * CAT + f];
    __syncthreads();
    if (tid < 60) {
        int n = tid / DSS, d = tid - n * DSS;
        float acc = 0.f;
        for (int i = 0; i < INS; ++i) acc += sW1[n * INS + i] * sWd[i * DSS + d];
        Wzc[j * KZ + tid] = f2bf(acc);
    } else {
        Wzc[j * KZ + tid] = 0;
    }
    for (int q = tid; q < HID; q += 64)
        Wzc[j * KZ + 64 + q] = f2bf(W1[(size_t)j * CAT + 2560 + q]);
    float acc = 0.f;
    for (int p = tid; p < 2560; p += 64) acc += sW1[p] * bd[p & (INS - 1)];
    red[tid] = acc;
    __syncthreads();
    for (int s = 32; s > 0; s >>= 1) {
        if (tid < s) red[tid] += red[tid + s];
        __syncthreads();
    }
    if (tid == 0) bfold[j] = b1[j] + red[0];
}

__global__ __launch_bounds__(256) void k_dfold(
    const float* __restrict__ desc, ushort_t* __restrict__ Dfold)
{
    int idx = blockIdx.x * 256 + threadIdx.x;
    int p = idx & 63;
    int tb = idx >> 6;
    int t = tb / BSZ;
    int b = tb - t * BSZ;
    float v = (p < 60) ? desc[(size_t)b * (TT * 60) + t * 60 + p] : 0.f;
    Dfold[idx] = f2bf(v);
}

__global__ __launch_bounds__(256) void k_prep_g(
    const float* __restrict__ Wih, const float* __restrict__ Whh,
    const float* __restrict__ bih, const float* __restrict__ bhh,
    ushort_t* __restrict__ Wg, float* __restrict__ bg)
{
    int idx = blockIdx.x * 256 + threadIdx.x;   // 1024*512
    int newr = idx >> 9, k = idx & 511;
    int j = newr >> 2, g = newr & 3;
    int src_row = g * 256 + j;
    float v = (k < 256) ? Wih[(size_t)src_row * INS + k]
                        : Whh[(size_t)src_row * HID + (k - 256)];
    Wg[idx] = f2bf(v);
    if (k == 0) bg[newr] = bih[src_row] + bhh[src_row];
}

__global__ __launch_bounds__(256) void k_prep_o(
    const float* __restrict__ W2, const float* __restrict__ Wv,
    ushort_t* __restrict__ Wout)
{
    int idx = blockIdx.x * 256 + threadIdx.x;   // 320*2816
    int r = idx / CAT, k = idx - r * CAT;
    float v = 0.f;
    if (r < 256) v = W2[(size_t)r * CAT + k];
    else if (r < NOUT) v = Wv[(size_t)(r - 256) * CAT + k];
    Wout[idx] = f2bf(v);
}

// ---------------------------------------------------------------------------
// FLAG-ARRAY group barrier (replaces round-8 single-counter RMW barrier).
// Each of the 8 slice-blocks owns a private 64-B flag line; arrival = one
// relaxed sc1 store of a monotonically increasing epoch (parallel, no RMW
// serialization); detection = wave-0 lanes polling the 8 peer flags -> one
// LLC round trip after the last arrival. Epochs never repeat -> no reset.
// ---------------------------------------------------------------------------
__device__ __forceinline__ void gbar(unsigned int* gfl, int s, unsigned int e) {
    __syncthreads();   // drains vmcnt: block's sc1 data stores complete
    if (threadIdx.x < 64) {
        if (threadIdx.x == 0) ASTORE(&gfl[s * 16], e);
        const int peer = threadIdx.x & 7;
        while (ALOAD(&gfl[peer * 16]) < e)
            __builtin_amdgcn_s_sleep(1);
    }
    __syncthreads();
}

// ---------------------------------------------------------------------------
// Persistent kernel. Block = (s = bid&7 slice, grp = bid>>3 -> 16 batch rows).
// 3 per-group flag barriers/step; sc1 staging reads batched dwordx4.
// (Identical compute structure to round 8, which passed at absmax 0.0039.)
// ---------------------------------------------------------------------------
__global__ void __launch_bounds__(NTHR) k_persist(
    const ushort_t* __restrict__ Wg, const float* __restrict__ bg,
    const ushort_t* __restrict__ Wzc, const float* __restrict__ bfold,
    const ushort_t* __restrict__ Wout, const float* __restrict__ b2,
    const float* __restrict__ bv, const ushort_t* __restrict__ Dfold,
    ushort_t* __restrict__ xh,          // [512][768]: inp | h(even) | h(odd)
    float* __restrict__ partA, float* __restrict__ partB,
    float* __restrict__ out, unsigned int* __restrict__ bars)
{
    __shared__ ushort_t sxh[16 * 520];   // B: [inp|h_prev], K=512, stride 520
    __shared__ ushort_t sa[16 * 328];    // C: [d|h_cur],   K=320, stride 328
    __shared__ ushort_t zt[16 * 360];    // C: z tile 16x352, stride 360
    __shared__ float    sg[16 * 132];    // B: gate staging
    __shared__ float    cl[16 * 33];     // cell state slice

    const int bid = blockIdx.x;
    const int tid = threadIdx.x;
    const int w = tid >> 6, l = tid & 63, quad = l >> 4, lr = l & 15;
    const int s = bid & 7, grp = bid >> 3, m0 = grp * 16;
    unsigned int* xh_u  = (unsigned int*)xh;    // row stride 384 uints
    unsigned int* sxh_u = (unsigned int*)sxh;
    unsigned int* sa_u  = (unsigned int*)sa;
    unsigned int* gfl = bars + grp * 128;       // 8 flags x 16 uints (64 B)

    // init: zero own col-slice of group's 16 xh rows + own c slice
    for (int i = tid; i < 16 * 33; i += NTHR) cl[i] = 0.f;
    if (tid < 192) {
        int row = tid / 12, v = tid % 12;
        int q = s * 48 + v * 4;
        #pragma unroll
        for (int k = 0; k < 4; ++k)
            ASTORE(&xh_u[(size_t)(m0 + row) * 384 + q + k], 0u);
    }
    gbar(gfl, s, 1);

    for (int t = 0; t < TT; ++t) {
        const int hcur  = 256 + (t & 1) * 256;
        const int hprev = 256 + ((t + 1) & 1) * 256;
        float*       pw = (t & 1) ? partB : partA;
        const float* pr = (t & 1) ? partA : partB;

        // ============ Phase A: reduce partials -> inp, out[t-1] ============
        if (t > 0) {
            int row = -1, chunk = 0;
            if (s < 6 && tid < 160)      { row = tid / 10; chunk = tid % 10; }
            else if (s == 6 && tid < 64) { row = tid >> 2; chunk = tid & 3; }
            if (row >= 0) {
                const int c0 = s * 40 + chunk * 4;
                f4 a[4], b[4];
                const float* base = &pr[((size_t)(m0 + row)) * 320 + c0];
                aload16x4(a, base + (size_t)0 * 512 * 320, base + (size_t)1 * 512 * 320,
                             base + (size_t)2 * 512 * 320, base + (size_t)3 * 512 * 320);
                aload16x4(b, base + (size_t)4 * 512 * 320, base + (size_t)5 * 512 * 320,
                             base + (size_t)6 * 512 * 320, base + (size_t)7 * 512 * 320);
                f4 sum = a[0] + a[1] + a[2] + a[3] + b[0] + b[1] + b[2] + b[3];
                f4 bb = *(const f4*)&b2[c0];
                unsigned int v0 = (unsigned int)f2bf(fmaxf(sum[0] + bb[0], 0.f))
                    | ((unsigned int)f2bf(fmaxf(sum[1] + bb[1], 0.f)) << 16);
                unsigned int v1 = (unsigned int)f2bf(fmaxf(sum[2] + bb[2], 0.f))
                    | ((unsigned int)f2bf(fmaxf(sum[3] + bb[3], 0.f)) << 16);
                ASTORE(&xh_u[(size_t)(m0 + row) * 384 + (c0 >> 1)], v0);
                ASTORE(&xh_u[(size_t)(m0 + row) * 384 + (c0 >> 1) + 1], v1);
            }
            if (s == 6 && tid >= 512 && tid < 672) {
                int k = tid - 512, r2 = k / 10, col = k - r2 * 10;
                float sum = 0.f;
                #pragma unroll
                for (int s2 = 0; s2 < 8; ++s2)
                    sum += ALOAD(&pr[((size_t)(s2 * 512 + m0 + r2)) * 320 + 256 + col]);
                out[(size_t)(m0 + r2) * (TT * NDD) + (t - 1) * NDD + col] =
                    sigf(sum + bv[col]);
            }
            gbar(gfl, s, 3 * t + 2);
        }

        // ============ Phase B: gates slice + cell ==========================
        {
            int row = tid >> 6, q4 = tid & 63;
            const unsigned int* src = (q4 < 32)
                ? &xh_u[(size_t)(m0 + row) * 384 + q4 * 4]
                : &xh_u[(size_t)(m0 + row) * 384 + (hprev >> 1) + (q4 - 32) * 4];
            *(u4*)&sxh_u[row * 260 + q4 * 4] = aload16(src);
        }
        __syncthreads();
        {
            const int tile = w & 7, kh = w >> 3;
            f4 acc = {};
            const ushort_t* bp = Wg + (size_t)(s * 128 + tile * 16 + lr) * 512
                               + kh * 256 + quad * 8;
            const ushort_t* ap = &sxh[lr * 520 + kh * 256 + quad * 8];
            #pragma unroll
            for (int ks = 0; ks < 8; ++ks)
                acc = MFMA(*(const sh8*)(ap + ks * 32), *(const sh8*)(bp + ks * 32), acc);
            if (kh == 0) {
                #pragma unroll
                for (int r = 0; r < 4; ++r)
                    sg[(quad * 4 + r) * 132 + tile * 16 + lr] = acc[r];
            }
            __syncthreads();
            if (kh == 1) {
                #pragma unroll
                for (int r = 0; r < 4; ++r)
                    sg[(quad * 4 + r) * 132 + tile * 16 + lr] += acc[r];
            }
            __syncthreads();
            if (tid < 256) {
                int row = tid >> 4, jp = tid & 15;
                float g8[8];
                #pragma unroll
                for (int i = 0; i < 8; ++i)
                    g8[i] = sg[row * 132 + jp * 8 + i] + bg[s * 128 + jp * 8 + i];
                unsigned int pair = 0;
                #pragma unroll
                for (int h2 = 0; h2 < 2; ++h2) {
                    float ai = g8[h2 * 4 + 0], af = g8[h2 * 4 + 1];
                    float ag = g8[h2 * 4 + 2], ao = g8[h2 * 4 + 3];
                    int jc = jp * 2 + h2;
                    float cc = sigf(af) * cl[row * 33 + jc] + sigf(ai) * tanhf(ag);
                    cl[row * 33 + jc] = cc;
                    float hh = sigf(ao) * tanhf(cc);
                    pair |= ((unsigned int)f2bf(hh)) << (16 * h2);
                }
                ASTORE(&xh_u[(size_t)(m0 + row) * 384 + (hcur >> 1) + s * 16 + jp], pair);
            }
        }
        gbar(gfl, s, 3 * t + 3);

        // ============ Phase C: z slice + OF partials =======================
        if (tid < 128) {
            int row = tid >> 3, v = tid & 7;
            *(u4*)&sa_u[row * 164 + v * 4] =
                *(const u4*)&Dfold[((size_t)t * BSZ + m0 + row) * 64 + v * 8];
        } else if (tid >= 256 && tid < 768) {
            int k = tid - 256;
            int row = k >> 5, v = k & 31;
            *(u4*)&sa_u[row * 164 + 32 + v * 4] =
                aload16(&xh_u[(size_t)(m0 + row) * 384 + (hcur >> 1) + v * 4]);
        }
        __syncthreads();
        for (int tl = w; tl < 22; tl += 16) {
            int n0g = s * 352 + tl * 16;
            f4 acc = {};
            const ushort_t* bp = Wzc + (size_t)(n0g + lr) * KZ + quad * 8;
            const ushort_t* ap = &sa[lr * 328 + quad * 8];
            #pragma unroll
            for (int ks = 0; ks < 10; ++ks)
                acc = MFMA(*(const sh8*)(ap + ks * 32), *(const sh8*)(bp + ks * 32), acc);
            float bia = bfold[n0g + lr];
            #pragma unroll
            for (int r = 0; r < 4; ++r)
                zt[(quad * 4 + r) * 360 + tl * 16 + lr] = f2bf(fmaxf(acc[r] + bia, 0.f));
        }
        __syncthreads();
        for (int tl = w; tl < 20; tl += 16) {
            int n0 = tl * 16;
            f4 acc = {};
            const ushort_t* bp = Wout + (size_t)(n0 + lr) * CAT + s * 352 + quad * 8;
            const ushort_t* ap = &zt[lr * 360 + quad * 8];
            #pragma unroll
            for (int ks = 0; ks < 11; ++ks)
                acc = MFMA(*(const sh8*)(ap + ks * 32), *(const sh8*)(bp + ks * 32), acc);
            #pragma unroll
            for (int r = 0; r < 4; ++r)
                ASTORE(&pw[((size_t)(s * 512 + m0 + quad * 4 + r)) * 320 + n0 + lr],
                       acc[r]);
        }
        gbar(gfl, s, 3 * t + 4);
    }

    // final out row (t = TT-1): partials in partB
    if (s == 6 && tid < 160) {
        int row = tid / 10, col = tid - row * 10;
        float sum = 0.f;
        #pragma unroll
        for (int s2 = 0; s2 < 8; ++s2)
            sum += ALOAD(&partB[((size_t)(s2 * 512 + m0 + row)) * 320 + 256 + col]);
        out[(size_t)(m0 + row) * (TT * NDD) + (TT - 1) * NDD + col] = sigf(sum + bv[col]);
    }
}

// ---------------------------------------------------------------------------
extern "C" void kernel_launch(void* const* d_in, const int* in_sizes, int n_in,
                              void* d_out, int out_size, void* d_ws, size_t ws_size,
                              hipStream_t stream)
{
    const float* desc = (const float*)d_in[0];
    const float* Wd   = (const float*)d_in[1];
    const float* bd   = (const float*)d_in[2];
    const float* W1   = (const float*)d_in[3];
    const float* b1   = (const float*)d_in[4];
    const float* W2   = (const float*)d_in[5];
    const float* b2   = (const float*)d_in[6];
    const float* Wv   = (const float*)d_in[7];
    const float* bv   = (const float*)d_in[8];
    const float* Wih  = (const float*)d_in[9];
    const float* Whh  = (const float*)d_in[10];
    const float* bih  = (const float*)d_in[11];
    const float* bhh  = (const float*)d_in[12];
    float* out = (float*)d_out;

    char* base = (char*)d_ws;
    size_t off = 0;
    auto alloc = [&](size_t bytes) -> char* {
        char* p = base + off;
        off = (off + bytes + 255) & ~(size_t)255;
        return p;
    };
    ushort_t*     Wzc   = (ushort_t*)alloc((size_t)CAT * KZ * 2);
    float*        bfold = (float*)alloc(CAT * 4);
    ushort_t*     Wg    = (ushort_t*)alloc(1024 * 512 * 2);
    float*        bg    = (float*)alloc(1024 * 4);
    ushort_t*     Wout  = (ushort_t*)alloc((size_t)NOUTP * CAT * 2);
    ushort_t*     Dfold = (ushort_t*)alloc((size_t)TT * BSZ * 64 * 2);
    ushort_t*     xh    = (ushort_t*)alloc((size_t)BSZ * 768 * 2);
    float*        partA = (float*)alloc((size_t)8 * BSZ * NOUTP * 4);
    float*        partB = (float*)alloc((size_t)8 * BSZ * NOUTP * 4);
    unsigned int* bars  = (unsigned int*)alloc(32 * 128 * 4);   // 32 grp x 8 flags x 64 B

    hipMemsetAsync(bars, 0, 32 * 128 * 4, stream);

    k_fold  <<<CAT, 64, 0, stream>>>(W1, Wd, bd, b1, Wzc, bfold);
    k_dfold <<<(TT * BSZ * 64) / 256, 256, 0, stream>>>(desc, Dfold);
    k_prep_g<<<(1024 * 512) / 256, 256, 0, stream>>>(Wih, Whh, bih, bhh, Wg, bg);
    k_prep_o<<<(NOUTP * CAT) / 256, 256, 0, stream>>>(W2, Wv, Wout);

    void* args[] = {
        (void*)&Wg, (void*)&bg, (void*)&Wzc, (void*)&bfold, (void*)&Wout,
        (void*)&b2, (void*)&bv, (void*)&Dfold, (void*)&xh,
        (void*)&partA, (void*)&partB, (void*)&out, (void*)&bars
    };
    hipLaunchCooperativeKernel((const void*)k_persist, dim3(NBLK), dim3(NTHR),
                               args, 0, stream);
}